// Round 7
// baseline (281.828 us; speedup 1.0000x reference)
//
#include <hip/hip_runtime.h>
#include <cstdint>
#include <cstddef>

typedef __bf16 bf16;
typedef bf16 bf16x8 __attribute__((ext_vector_type(8)));
typedef bf16 bf16x4 __attribute__((ext_vector_type(4)));
typedef bf16 bf16x2 __attribute__((ext_vector_type(2)));
typedef float f32x4 __attribute__((ext_vector_type(4)));
typedef float f32x16 __attribute__((ext_vector_type(16)));
typedef uint32_t u32x2 __attribute__((ext_vector_type(2)));
typedef uint32_t u32x4 __attribute__((ext_vector_type(4)));

#define DEVI __device__ __forceinline__

// ---------------- constants ----------------
// B=4, T=2048, D=1152, H=8, HD=144, BT=8192
#define CB 4
#define CT 2048
#define CD 1152
#define CH 8
#define CHD 144
#define CBT 8192

DEVI void gload_lds16(const void* g, void* l) {
  __builtin_amdgcn_global_load_lds(
      (const __attribute__((address_space(1))) void*)g,
      (__attribute__((address_space(3))) void*)l, 16, 0, 0);
}

DEVI f32x4 mfma16(bf16x8 a, bf16x8 b, f32x4 c) {
  return __builtin_amdgcn_mfma_f32_16x16x32_bf16(a, b, c, 0, 0, 0);
}
DEVI f32x16 mfma32(bf16x8 a, bf16x8 b, f32x16 c) {
  return __builtin_amdgcn_mfma_f32_32x32x16_bf16(a, b, c, 0, 0, 0);
}

DEVI uint32_t cvtpk(float lo, float hi) {
  uint32_t r;
  asm("v_cvt_pk_bf16_f32 %0, %1, %2" : "=v"(r) : "v"(lo), "v"(hi));
  return r;
}

DEVI f32x16 zero16() {
  f32x16 z;
#pragma unroll
  for (int i = 0; i < 16; ++i) z[i] = 0.f;
  return z;
}

// ---------------- cast f32 -> bf16 (8 els / thread) ----------------
__global__ __launch_bounds__(256) void k_cast(const float* __restrict__ in,
                                              bf16* __restrict__ out, int n8) {
  int i = blockIdx.x * 256 + threadIdx.x;
  if (i >= n8) return;
  const float4* p = (const float4*)in + (size_t)i * 2;
  float4 a = p[0], b = p[1];
  bf16x8 o;
  o[0] = (bf16)a.x; o[1] = (bf16)a.y; o[2] = (bf16)a.z; o[3] = (bf16)a.w;
  o[4] = (bf16)b.x; o[5] = (bf16)b.y; o[6] = (bf16)b.z; o[7] = (bf16)b.w;
  ((bf16x8*)out)[i] = o;
}

// 4 weight casts in one launch (blockIdx.y selects tensor)
__global__ __launch_bounds__(256) void k_cast4(
    const float* __restrict__ a, const float* __restrict__ b,
    const float* __restrict__ c, const float* __restrict__ d,
    bf16* __restrict__ oa, bf16* __restrict__ ob,
    bf16* __restrict__ oc, bf16* __restrict__ od, int n8) {
  int w = blockIdx.y;
  const float* in = (w == 0) ? a : (w == 1) ? b : (w == 2) ? c : d;
  bf16* out = (w == 0) ? oa : (w == 1) ? ob : (w == 2) ? oc : od;
  int i = blockIdx.x * 256 + threadIdx.x;
  if (i >= n8) return;
  const float4* p = (const float4*)in + (size_t)i * 2;
  float4 x = p[0], y = p[1];
  bf16x8 o;
  o[0] = (bf16)x.x; o[1] = (bf16)x.y; o[2] = (bf16)x.z; o[3] = (bf16)x.w;
  o[4] = (bf16)y.x; o[5] = (bf16)y.y; o[6] = (bf16)y.z; o[7] = (bf16)y.w;
  ((bf16x8*)out)[i] = o;
}

// ---------------- GEMM C[M,N] = A[M,K] * W[N,K]^T  (bf16 in, f32 acc) ----------------
// bm0/bn0 supplied by wrapper (XCD-swizzled).
template <bool BF16_OUT>
DEVI void gemm_body(const bf16* __restrict__ A, const bf16* __restrict__ W,
                    void* __restrict__ Cout, int M, int N, int K,
                    int bm0, int bn0) {
  __shared__ __align__(16) bf16 As[128 * 40];
  __shared__ __align__(16) bf16 Bs[128 * 40];
  const int tid = threadIdx.x;
  const int lane = tid & 63, wid = tid >> 6;
  const int l15 = lane & 15, g = lane >> 4;
  const int wm = wid >> 1, wn = wid & 1;

  f32x4 acc[4][4];
  for (int mi = 0; mi < 4; ++mi)
    for (int ni = 0; ni < 4; ++ni) {
      acc[mi][ni][0] = 0.f; acc[mi][ni][1] = 0.f;
      acc[mi][ni][2] = 0.f; acc[mi][ni][3] = 0.f;
    }

  const int nk = K >> 5;
  for (int kt = 0; kt < nk; ++kt) {
    const int k0 = kt << 5;
    for (int c = 0; c < 3; ++c) {
      int li = tid + (c << 8);
      if (li < 640) {
        int e0 = li << 3;
        int row = e0 / 40, col = e0 % 40;
        if (col >= 32) col = 24;
        gload_lds16(&A[(size_t)(bm0 + row) * K + k0 + col], As + (size_t)(li & ~63) * 8);
        gload_lds16(&W[(size_t)(bn0 + row) * K + k0 + col], Bs + (size_t)(li & ~63) * 8);
      }
    }
    __syncthreads();

    bf16x8 af[4], bfr[4];
    for (int mi = 0; mi < 4; ++mi)
      af[mi] = *(const bf16x8*)&As[(wm * 64 + mi * 16 + l15) * 40 + g * 8];
    for (int ni = 0; ni < 4; ++ni)
      bfr[ni] = *(const bf16x8*)&Bs[(wn * 64 + ni * 16 + l15) * 40 + g * 8];
    __builtin_amdgcn_s_setprio(1);
    for (int mi = 0; mi < 4; ++mi)
      for (int ni = 0; ni < 4; ++ni)
        acc[mi][ni] = mfma16(af[mi], bfr[ni], acc[mi][ni]);
    __builtin_amdgcn_s_setprio(0);
    __syncthreads();
  }

  for (int mi = 0; mi < 4; ++mi)
    for (int ni = 0; ni < 4; ++ni)
      for (int r = 0; r < 4; ++r) {
        int rowg = bm0 + wm * 64 + mi * 16 + g * 4 + r;
        int colg = bn0 + wn * 64 + ni * 16 + l15;
        float v = acc[mi][ni][r];
        if (BF16_OUT)
          ((bf16*)Cout)[(size_t)rowg * N + colg] = (bf16)v;
        else
          ((float*)Cout)[(size_t)rowg * N + colg] = v;
      }
}

__global__ __launch_bounds__(256) void k_gemm_qkv(
    const bf16* __restrict__ A, const bf16* __restrict__ Wq,
    const bf16* __restrict__ Wk, const bf16* __restrict__ Wv,
    bf16* __restrict__ q, bf16* __restrict__ k, bf16* __restrict__ v) {
  // T1 bijective XCD swizzle (nwg = 1728, %8 == 0)
  const int nx = gridDim.x, ny = gridDim.y;
  const int nwg = nx * ny * gridDim.z;
  const int orig = (blockIdx.z * ny + blockIdx.y) * nx + blockIdx.x;
  const int logical = (orig & 7) * (nwg >> 3) + (orig >> 3);
  const int lx = logical % nx;
  const int rest = logical / nx;
  const int ly = rest % ny, lz = rest / ny;
  const bf16* W = (lz == 0) ? Wq : (lz == 1) ? Wk : Wv;
  bf16* out = (lz == 0) ? q : (lz == 1) ? k : v;
  gemm_body<true>(A, W, out, CBT, CD, CD, ly * 128, lx * 128);
}

__global__ __launch_bounds__(256) void k_gemm_out(
    const bf16* __restrict__ A, const bf16* __restrict__ W, float* __restrict__ out) {
  const int nx = gridDim.x, ny = gridDim.y;
  const int nwg = nx * ny;
  const int orig = blockIdx.y * nx + blockIdx.x;
  const int logical = (orig & 7) * (nwg >> 3) + (orig >> 3);
  const int lx = logical % nx, ly = logical / nx;
  gemm_body<false>(A, W, out, CBT, CD, CD, ly * 128, lx * 128);
}

// ---------------- rotary, in place; q scaled by HD^-0.5 * log2(e) ----------------
// (S = q·k then lands directly in log2 units -> exp2 without per-element mul)
__global__ __launch_bounds__(256) void k_rotary(bf16* __restrict__ q, bf16* __restrict__ k,
                                                const float* __restrict__ cosb,
                                                const float* __restrict__ sinb) {
  const int bt = blockIdx.x;
  const int t = bt & (CT - 1);
  const size_t rowoff = (size_t)bt * CD;
  const float* cr = cosb + (size_t)t * CHD;
  const float* sr = sinb + (size_t)t * CHD;
  for (int i = threadIdx.x; i < 288; i += 256) {
    int tensor = i / 144;
    int rem = i - tensor * 144;
    int h = rem / 18, jg = rem % 18;
    int j = jg * 4;
    float scl = tensor ? 1.0f : 0.120224587f;  // SCALE * log2(e) folded into q
    bf16* base = (tensor ? k : q) + rowoff + h * CHD;
    bf16x4 a = *(bf16x4*)&base[j];
    bf16x4 b2 = *(bf16x4*)&base[j + 72];
    f32x4 c1 = *(const f32x4*)&cr[j];
    f32x4 s1 = *(const f32x4*)&sr[j];
    f32x4 c2 = *(const f32x4*)&cr[j + 72];
    f32x4 s2 = *(const f32x4*)&sr[j + 72];
    bf16x4 o1, o2;
    for (int r = 0; r < 4; ++r) {
      float av = (float)a[r], bv = (float)b2[r];
      o1[r] = (bf16)((av * c1[r] - bv * s1[r]) * scl);
      o2[r] = (bf16)((bv * c2[r] + av * s2[r]) * scl);
    }
    *(bf16x4*)&base[j] = o1;
    *(bf16x4*)&base[j + 72] = o2;
  }
}

// ---------------- V transpose: v_lin[b][t][h*144+hd] -> vT[bh][hd][t] ----------------
__global__ __launch_bounds__(256) void k_vtrans(const bf16* __restrict__ v, bf16* __restrict__ vT) {
  __shared__ bf16 tile[64][152];
  const int bh = blockIdx.y;
  const int b = bh >> 3, h = bh & 7;
  const int t0 = blockIdx.x * 64;
  for (int i8 = threadIdx.x; i8 < 64 * 18; i8 += 256) {
    int r = i8 / 18, c8 = i8 % 18;
    *(bf16x8*)&tile[r][c8 * 8] =
        *(const bf16x8*)&v[((size_t)(b * CT + t0 + r)) * CD + h * CHD + c8 * 8];
  }
  __syncthreads();
  for (int o = threadIdx.x; o < CHD * 64; o += 256) {
    int hd = o / 64, j = o & 63;
    vT[((size_t)(bh * CHD + hd)) * CT + t0 + j] = tile[j][hd];
  }
}

// ---------------- P fragment builder: S^T C-regs -> PV B-frags, in-register ----------
// s is in log2 units (LOG2E folded into q at rotary).
DEVI void build_pfrag(const f32x16& s, float m, float& ps, bf16x8& f0, bf16x8& f1) {
  uint32_t pk[8];
#pragma unroll
  for (int a = 0; a < 8; ++a) {
    float p0 = exp2f(s[2 * a] - m);
    float p1 = exp2f(s[2 * a + 1] - m);
    ps += p0 + p1;
    pk[a] = cvtpk(p0, p1);
  }
  u32x2 r02 = __builtin_amdgcn_permlane32_swap(pk[0], pk[2], false, false);
  u32x2 r13 = __builtin_amdgcn_permlane32_swap(pk[1], pk[3], false, false);
  u32x2 r46 = __builtin_amdgcn_permlane32_swap(pk[4], pk[6], false, false);
  u32x2 r57 = __builtin_amdgcn_permlane32_swap(pk[5], pk[7], false, false);
  u32x4 w0 = {r02[0], r13[0], r02[1], r13[1]};
  u32x4 w1 = {r46[0], r57[0], r46[1], r57[1]};
  f0 = __builtin_bit_cast(bf16x8, w0);
  f1 = __builtin_bit_cast(bf16x8, w1);
}

// ILP-friendly 32-element max over two f32x16 (quads -> tree; fusable to v_max3)
DEVI float max32(const f32x16& s0, const f32x16& s1) {
  float q0 = fmaxf(fmaxf(s0[0], s0[1]), fmaxf(s0[2], s0[3]));
  float q1 = fmaxf(fmaxf(s0[4], s0[5]), fmaxf(s0[6], s0[7]));
  float q2 = fmaxf(fmaxf(s0[8], s0[9]), fmaxf(s0[10], s0[11]));
  float q3 = fmaxf(fmaxf(s0[12], s0[13]), fmaxf(s0[14], s0[15]));
  float q4 = fmaxf(fmaxf(s1[0], s1[1]), fmaxf(s1[2], s1[3]));
  float q5 = fmaxf(fmaxf(s1[4], s1[5]), fmaxf(s1[6], s1[7]));
  float q6 = fmaxf(fmaxf(s1[8], s1[9]), fmaxf(s1[10], s1[11]));
  float q7 = fmaxf(fmaxf(s1[12], s1[13]), fmaxf(s1[14], s1[15]));
  return fmaxf(fmaxf(fmaxf(q0, q1), fmaxf(q2, q3)),
               fmaxf(fmaxf(q4, q5), fmaxf(q6, q7)));
}

// ---------------- flash attention: T3 dbuf pipeline + T15 softmax/MFMA overlap -----
// grid: 256 blocks (bh-XCD affinity), 512 threads = 8 waves x 32 q-rows (256 q/block).
// Ks[2][64][384B] (XOR-swizzled via pre-swizzled source). Vs[3][160][128B] (triple
// buffer: PV(t-1) reads V[(t-1)%3] while stage writes V[(t+1)%3] -> race-free with
// one barrier/iter). Per iter t: stage(t+1) | QK(t) [MFMA] || pfrag(t-1) [VALU]
// -> PV(t-1) [MFMA] || max(t) [VALU] -> deferred rescale.
__global__ __launch_bounds__(512, 2) void k_attn(const bf16* __restrict__ qg,
                                                 const bf16* __restrict__ kg,
                                                 const bf16* __restrict__ vT,
                                                 bf16* __restrict__ og) {
  const int lin = blockIdx.x;
  const int xcd = lin & 7, idx = lin >> 3;
  const int bh = ((idx & 3) << 3) | xcd;   // 4 heads per XCD -> K/V L2-resident
  const int qx = idx >> 2;
  const int b = bh >> 3, h = bh & 7;
  const int q0 = qx << 8;
  const int tid = threadIdx.x, lane = tid & 63, wq = tid >> 6;
  const int l31 = lane & 31, hi = lane >> 5;
  const int hi16 = hi * 16;
  const int kxor = (l31 & 7) << 4;

  constexpr int KBUF = 64 * 192;    // 12288 els = 24576 B
  constexpr int VBUF = 160 * 64;    // 10240 els = 20480 B
  __shared__ __align__(16) bf16 Ks[2 * KBUF];   // 49152 B
  __shared__ __align__(16) bf16 Vs[3 * VBUF];   // 61440 B  (total 110592 B)

  // Q fragments (B-frag: col=q=l31, k = ks*16 + hi*8 + e), 9 k-steps (144 = 9*16)
  bf16x8 qf[9];
  {
    const bf16* qbase = qg + (size_t)(b * CT + q0 + wq * 32 + l31) * CD + h * CHD + hi * 8;
#pragma unroll
    for (int ks = 0; ks < 9; ++ks) qf[ks] = *(const bf16x8*)&qbase[ks * 16];
  }

  // staging precompute: LDS dest linear, global source pre-swizzled (m173 pattern).
  const bf16* ksrc[3];
  const bf16* vsrc[3];
  int kldo[3], vldo[3];
#pragma unroll
  for (int it = 0; it < 3; ++it) {
    int c = tid + it * 512;
    int krow = c / 24, kj = c - krow * 24;
    int kcol = (kj * 16) ^ ((krow & 7) << 4);
    if (kcol >= 288) kcol = 0;  // pad slot: valid addr, never read
    ksrc[it] = kg + (size_t)(b * CT + krow) * CD + h * CHD + (kcol >> 1);
    kldo[it] = ((tid & ~63) + it * 512) * 8;
    int vr = c >> 3, vj = c & 7;
    int vcol = (vj * 16) ^ ((vr & 7) << 4);
    if (vr > 143) vr = 143;  // it2 tail unused (guarded), keep ptr valid
    vsrc[it] = vT + (size_t)(bh * CHD + vr) * CT + (vcol >> 1);
    vldo[it] = ((tid & ~63) + it * 512) * 8;
  }
  const bool vok2 = (tid < 128);  // wave-uniform guard for V chunk set #2

  // zero V pad rows (144..159) in all THREE buffers
  if (tid < 384) {
    u32x4 z = {0u, 0u, 0u, 0u};
    int bsel = tid >> 7, off = tid & 127;
    *(u32x4*)(Vs + bsel * VBUF + 144 * 64 + off * 8) = z;
  }

#define STAGE_TILE(kv, kb, vb)                                              \
  do {                                                                      \
    bf16* Kn = Ks + (kb) * KBUF;                                            \
    bf16* Vn = Vs + (vb) * VBUF;                                            \
    _Pragma("unroll") for (int it = 0; it < 3; ++it)                        \
        gload_lds16(ksrc[it] + (size_t)(kv) * CD, Kn + kldo[it]);           \
    _Pragma("unroll") for (int it = 0; it < 2; ++it)                        \
        gload_lds16(vsrc[it] + (kv), Vn + vldo[it]);                        \
    if (vok2) gload_lds16(vsrc[2] + (kv), Vn + vldo[2]);                    \
  } while (0)

  // prologue: stage tile 0
  STAGE_TILE(0, 0, 0);
  __syncthreads();  // tile 0 + pad zeros visible

  f32x16 oacc[5];
#pragma unroll
  for (int u = 0; u < 5; ++u) oacc[u] = zero16();
  float lsum = 0.f;
  float m;
  f32x16 sp0, sp1;  // S of previous tile (pipelined)

  // ---- iter 0: stage(1); QK(0); max; (no pfrag/PV yet) ----
  {
    STAGE_TILE(64, 1, 1);
    __builtin_amdgcn_sched_barrier(0);
    const char* kr0 = (const char*)Ks + (size_t)l31 * 384;
    const char* kr1 = kr0 + 32 * 384;
    sp0 = zero16(); sp1 = zero16();
    __builtin_amdgcn_s_setprio(1);
#pragma unroll
    for (int ks = 0; ks < 9; ++ks) {
      int off = (ks * 32 + hi16) ^ kxor;
      sp0 = mfma32(*(const bf16x8*)(kr0 + off), qf[ks], sp0);
      sp1 = mfma32(*(const bf16x8*)(kr1 + off), qf[ks], sp1);
    }
    __builtin_amdgcn_s_setprio(0);
    float mt = max32(sp0, sp1);
    mt = fmaxf(mt, __shfl_xor(mt, 32));
    m = mt;
    __syncthreads();
  }

  // ---- main loop t = 1..31 ----
  for (int t = 1; t < 32; ++t) {
    if (t < 31) STAGE_TILE((t + 1) << 6, (t + 1) & 1, (t + 1) % 3);
    __builtin_amdgcn_sched_barrier(0);

    // QK(t) from K[t&1]  [MFMA]  -- independent of pfrag(t-1) [VALU] below
    const char* kr0 = (const char*)(Ks + (t & 1) * KBUF) + (size_t)l31 * 384;
    const char* kr1 = kr0 + 32 * 384;
    f32x16 sn0 = zero16(), sn1 = zero16();
    __builtin_amdgcn_s_setprio(1);
#pragma unroll
    for (int ks = 0; ks < 9; ++ks) {
      int off = (ks * 32 + hi16) ^ kxor;
      sn0 = mfma32(*(const bf16x8*)(kr0 + off), qf[ks], sn0);
      sn1 = mfma32(*(const bf16x8*)(kr1 + off), qf[ks], sn1);
    }
    __builtin_amdgcn_s_setprio(0);

    // pfrag(t-1) [VALU] — overlaps QK's MFMA pipe
    float ps = 0.f;
    bf16x8 pf0, pf1, pf2, pf3;
    build_pfrag(sp0, m, ps, pf0, pf1);
    build_pfrag(sp1, m, ps, pf2, pf3);
    ps += __shfl_xor(ps, 32);
    lsum += ps;

    // PV(t-1) from V[(t-1)%3]  [MFMA]
    const bf16* Vc = Vs + ((t - 1) % 3) * VBUF;
    __builtin_amdgcn_s_setprio(1);
#pragma unroll
    for (int u = 0; u < 5; ++u) {
      const char* vrow = (const char*)Vc + (size_t)(u * 32 + l31) * 128;
      oacc[u] = mfma32(*(const bf16x8*)(vrow + ((0 * 32 + hi16) ^ kxor)), pf0, oacc[u]);
      oacc[u] = mfma32(*(const bf16x8*)(vrow + ((1 * 32 + hi16) ^ kxor)), pf1, oacc[u]);
      oacc[u] = mfma32(*(const bf16x8*)(vrow + ((2 * 32 + hi16) ^ kxor)), pf2, oacc[u]);
      oacc[u] = mfma32(*(const bf16x8*)(vrow + ((3 * 32 + hi16) ^ kxor)), pf3, oacc[u]);
    }
    __builtin_amdgcn_s_setprio(0);

    // max(t) [VALU] — overlaps PV's MFMA pipe; rescale after PV completes
    float mt = max32(sn0, sn1);
    mt = fmaxf(mt, __shfl_xor(mt, 32));
    if (mt > m + 8.0f) {  // defer-max (log2 units; P bounded by 2^8)
      float alpha = exp2f(m - mt);
      lsum *= alpha;
#pragma unroll
      for (int u = 0; u < 5; ++u) oacc[u] = oacc[u] * alpha;
      m = mt;
    }
    sp0 = sn0; sp1 = sn1;
    __syncthreads();
  }

  // ---- epilogue: pfrag + PV for tile 31 (V[31%3 = 1]) ----
  {
    float ps = 0.f;
    bf16x8 pf0, pf1, pf2, pf3;
    build_pfrag(sp0, m, ps, pf0, pf1);
    build_pfrag(sp1, m, ps, pf2, pf3);
    ps += __shfl_xor(ps, 32);
    lsum += ps;
    const bf16* Vc = Vs + (31 % 3) * VBUF;
#pragma unroll
    for (int u = 0; u < 5; ++u) {
      const char* vrow = (const char*)Vc + (size_t)(u * 32 + l31) * 128;
      oacc[u] = mfma32(*(const bf16x8*)(vrow + ((0 * 32 + hi16) ^ kxor)), pf0, oacc[u]);
      oacc[u] = mfma32(*(const bf16x8*)(vrow + ((1 * 32 + hi16) ^ kxor)), pf1, oacc[u]);
      oacc[u] = mfma32(*(const bf16x8*)(vrow + ((2 * 32 + hi16) ^ kxor)), pf2, oacc[u]);
      oacc[u] = mfma32(*(const bf16x8*)(vrow + ((3 * 32 + hi16) ^ kxor)), pf3, oacc[u]);
    }
  }
#undef STAGE_TILE

  // normalize + store: lane owns q-col = l31; C rows hd = u*32+(reg&3)+8*(reg>>2)+4*hi
  float inv = 1.0f / lsum;
  bf16* ob = og + (size_t)(b * CT + q0 + wq * 32 + l31) * CD + h * CHD;
#pragma unroll
  for (int u = 0; u < 5; ++u) {
#pragma unroll
    for (int pr = 0; pr < 8; ++pr) {
      if (u == 4 && pr >= 4) continue;  // hd >= 144 is pad
      int hd = u * 32 + ((2 * pr) & 3) + 8 * (pr >> 1) + 4 * hi;
      bf16x2 w;
      w[0] = (bf16)(oacc[u][2 * pr] * inv);
      w[1] = (bf16)(oacc[u][2 * pr + 1] * inv);
      *(bf16x2*)&ob[hd] = w;
    }
  }
}

// ---------------- launcher ----------------
extern "C" void kernel_launch(void* const* d_in, const int* in_sizes, int n_in,
                              void* d_out, int out_size, void* d_ws, size_t ws_size,
                              hipStream_t stream) {
  const float* x = (const float*)d_in[0];
  const float* cosb = (const float*)d_in[1];
  const float* sinb = (const float*)d_in[2];
  const float* Wq = (const float*)d_in[3];
  const float* Wk = (const float*)d_in[4];
  const float* Wv = (const float*)d_in[5];
  const float* Wo = (const float*)d_in[6];

  char* ws = (char*)d_ws;
  bf16* xb   = (bf16*)(ws + 0);           // reused as attention output (o_bt)
  bf16* wqb  = (bf16*)(ws + 18874368);
  bf16* wkb  = (bf16*)(ws + 21528576);
  bf16* wvb  = (bf16*)(ws + 24182784);
  bf16* wob  = (bf16*)(ws + 26836992);
  bf16* qlin = (bf16*)(ws + 29491200);
  bf16* klin = (bf16*)(ws + 48365568);
  bf16* vlin = (bf16*)(ws + 67239936);
  bf16* vT   = (bf16*)(ws + 86114304);

  // casts
  k_cast<<<4608, 256, 0, stream>>>(x, xb, CBT * CD / 8);
  k_cast4<<<dim3(648, 4), 256, 0, stream>>>(Wq, Wk, Wv, Wo, wqb, wkb, wvb, wob,
                                            CD * CD / 8);

  // QKV projections (fused over z, XCD-swizzled)
  k_gemm_qkv<<<dim3(CD / 128, CBT / 128, 3), 256, 0, stream>>>(xb, wqb, wkb, wvb,
                                                               qlin, klin, vlin);
  // rotary in place on q,k (q scaled by SCALE*log2e)
  k_rotary<<<CB * CT, 256, 0, stream>>>(qlin, klin, cosb, sinb);
  // V transpose
  k_vtrans<<<dim3(CT / 64, CB * CH), 256, 0, stream>>>(vlin, vT);
  // attention -> o (into xb region, [b][t][h*144+hd])
  k_attn<<<256, 512, 0, stream>>>(qlin, klin, vT, xb);
  // output projection (f32 out, XCD-swizzled)
  k_gemm_out<<<dim3(CD / 128, CBT / 128), 256, 0, stream>>>(xb, wob, (float*)d_out);
}

// Round 8
// 263.661 us; speedup vs baseline: 1.0689x; 1.0689x over previous
//
#include <hip/hip_runtime.h>
#include <cstdint>
#include <cstddef>

typedef __bf16 bf16;
typedef bf16 bf16x8 __attribute__((ext_vector_type(8)));
typedef bf16 bf16x4 __attribute__((ext_vector_type(4)));
typedef bf16 bf16x2 __attribute__((ext_vector_type(2)));
typedef float f32x4 __attribute__((ext_vector_type(4)));
typedef float f32x16 __attribute__((ext_vector_type(16)));
typedef uint32_t u32x2 __attribute__((ext_vector_type(2)));
typedef uint32_t u32x4 __attribute__((ext_vector_type(4)));

#define DEVI __device__ __forceinline__

// ---------------- constants ----------------
// B=4, T=2048, D=1152, H=8, HD=144, BT=8192
#define CB 4
#define CT 2048
#define CD 1152
#define CH 8
#define CHD 144
#define CBT 8192

DEVI void gload_lds16(const void* g, void* l) {
  __builtin_amdgcn_global_load_lds(
      (const __attribute__((address_space(1))) void*)g,
      (__attribute__((address_space(3))) void*)l, 16, 0, 0);
}

DEVI f32x4 mfma16(bf16x8 a, bf16x8 b, f32x4 c) {
  return __builtin_amdgcn_mfma_f32_16x16x32_bf16(a, b, c, 0, 0, 0);
}
DEVI f32x16 mfma32(bf16x8 a, bf16x8 b, f32x16 c) {
  return __builtin_amdgcn_mfma_f32_32x32x16_bf16(a, b, c, 0, 0, 0);
}

DEVI uint32_t cvtpk(float lo, float hi) {
  uint32_t r;
  asm("v_cvt_pk_bf16_f32 %0, %1, %2" : "=v"(r) : "v"(lo), "v"(hi));
  return r;
}

DEVI f32x16 zero16() {
  f32x16 z;
#pragma unroll
  for (int i = 0; i < 16; ++i) z[i] = 0.f;
  return z;
}

// ---------------- cast f32 -> bf16 (8 els / thread) ----------------
__global__ __launch_bounds__(256) void k_cast(const float* __restrict__ in,
                                              bf16* __restrict__ out, int n8) {
  int i = blockIdx.x * 256 + threadIdx.x;
  if (i >= n8) return;
  const float4* p = (const float4*)in + (size_t)i * 2;
  float4 a = p[0], b = p[1];
  bf16x8 o;
  o[0] = (bf16)a.x; o[1] = (bf16)a.y; o[2] = (bf16)a.z; o[3] = (bf16)a.w;
  o[4] = (bf16)b.x; o[5] = (bf16)b.y; o[6] = (bf16)b.z; o[7] = (bf16)b.w;
  ((bf16x8*)out)[i] = o;
}

// 4 weight casts in one launch (blockIdx.y selects tensor)
__global__ __launch_bounds__(256) void k_cast4(
    const float* __restrict__ a, const float* __restrict__ b,
    const float* __restrict__ c, const float* __restrict__ d,
    bf16* __restrict__ oa, bf16* __restrict__ ob,
    bf16* __restrict__ oc, bf16* __restrict__ od, int n8) {
  int w = blockIdx.y;
  const float* in = (w == 0) ? a : (w == 1) ? b : (w == 2) ? c : d;
  bf16* out = (w == 0) ? oa : (w == 1) ? ob : (w == 2) ? oc : od;
  int i = blockIdx.x * 256 + threadIdx.x;
  if (i >= n8) return;
  const float4* p = (const float4*)in + (size_t)i * 2;
  float4 x = p[0], y = p[1];
  bf16x8 o;
  o[0] = (bf16)x.x; o[1] = (bf16)x.y; o[2] = (bf16)x.z; o[3] = (bf16)x.w;
  o[4] = (bf16)y.x; o[5] = (bf16)y.y; o[6] = (bf16)y.z; o[7] = (bf16)y.w;
  ((bf16x8*)out)[i] = o;
}

// ---------------- GEMM C[M,N] = A[M,K] * W[N,K]^T  (bf16 in, f32 acc) ----------------
// 128x128 tile, BK=32, 2-phase double-buffered staging (T3 minimum recipe):
// prefetch tile kt+1 into buf^1 BEFORE computing tile kt; one barrier per iter.
template <bool BF16_OUT>
DEVI void gemm_body(const bf16* __restrict__ A, const bf16* __restrict__ W,
                    void* __restrict__ Cout, int M, int N, int K,
                    int bm0, int bn0) {
  constexpr int TBUF = 128 * 40;  // 5120 els = 10240 B per tensor per buffer
  __shared__ __align__(16) bf16 As[2 * TBUF];
  __shared__ __align__(16) bf16 Bs[2 * TBUF];
  const int tid = threadIdx.x;
  const int lane = tid & 63, wid = tid >> 6;
  const int l15 = lane & 15, g = lane >> 4;
  const int wm = wid >> 1, wn = wid & 1;

  // staging source precompute (li < 640 active chunks of 8 els)
  const bf16* asrc[3];
  const bf16* wsrc[3];
  int ldo[3];
  bool on[3];
#pragma unroll
  for (int c = 0; c < 3; ++c) {
    int li = tid + (c << 8);
    on[c] = (li < 640);
    int li2 = on[c] ? li : 0;
    int e0 = li2 << 3;
    int row = e0 / 40, col = e0 % 40;
    if (col >= 32) col = 24;  // pad slot: valid addr, never read as fragment
    asrc[c] = &A[(size_t)(bm0 + row) * K + col];
    wsrc[c] = &W[(size_t)(bn0 + row) * K + col];
    ldo[c] = (li2 & ~63) * 8;
  }

#define G_STAGE(k0, buf)                                                     \
  do {                                                                       \
    bf16* Ad = As + (buf)*TBUF;                                              \
    bf16* Bd = Bs + (buf)*TBUF;                                              \
    _Pragma("unroll") for (int c = 0; c < 3; ++c) if (on[c]) {               \
      gload_lds16(asrc[c] + (k0), Ad + ldo[c]);                              \
      gload_lds16(wsrc[c] + (k0), Bd + ldo[c]);                              \
    }                                                                        \
  } while (0)

  f32x4 acc[4][4];
  for (int mi = 0; mi < 4; ++mi)
    for (int ni = 0; ni < 4; ++ni) {
      acc[mi][ni][0] = 0.f; acc[mi][ni][1] = 0.f;
      acc[mi][ni][2] = 0.f; acc[mi][ni][3] = 0.f;
    }

  const int nk = K >> 5;  // 36
  G_STAGE(0, 0);
  __syncthreads();

  int cur = 0;
  for (int kt = 0; kt < nk; ++kt) {
    if (kt + 1 < nk) G_STAGE((kt + 1) << 5, cur ^ 1);
    __builtin_amdgcn_sched_barrier(0);  // pin prefetch issue before compute

    const bf16* Ac = As + cur * TBUF;
    const bf16* Bc = Bs + cur * TBUF;
    bf16x8 af[4], bfr[4];
    for (int mi = 0; mi < 4; ++mi)
      af[mi] = *(const bf16x8*)&Ac[(wm * 64 + mi * 16 + l15) * 40 + g * 8];
    for (int ni = 0; ni < 4; ++ni)
      bfr[ni] = *(const bf16x8*)&Bc[(wn * 64 + ni * 16 + l15) * 40 + g * 8];
    __builtin_amdgcn_s_setprio(1);
    for (int mi = 0; mi < 4; ++mi)
      for (int ni = 0; ni < 4; ++ni)
        acc[mi][ni] = mfma16(af[mi], bfr[ni], acc[mi][ni]);
    __builtin_amdgcn_s_setprio(0);
    __syncthreads();  // drains my prefetch (vm) + everyone's reads (lgkm)
    cur ^= 1;
  }
#undef G_STAGE

  for (int mi = 0; mi < 4; ++mi)
    for (int ni = 0; ni < 4; ++ni)
      for (int r = 0; r < 4; ++r) {
        int rowg = bm0 + wm * 64 + mi * 16 + g * 4 + r;
        int colg = bn0 + wn * 64 + ni * 16 + l15;
        float v = acc[mi][ni][r];
        if (BF16_OUT)
          ((bf16*)Cout)[(size_t)rowg * N + colg] = (bf16)v;
        else
          ((float*)Cout)[(size_t)rowg * N + colg] = v;
      }
}

__global__ __launch_bounds__(256) void k_gemm_qkv(
    const bf16* __restrict__ A, const bf16* __restrict__ Wq,
    const bf16* __restrict__ Wk, const bf16* __restrict__ Wv,
    bf16* __restrict__ q, bf16* __restrict__ k, bf16* __restrict__ v) {
  // T1 bijective XCD swizzle (nwg = 1728, %8 == 0)
  const int nx = gridDim.x, ny = gridDim.y;
  const int nwg = nx * ny * gridDim.z;
  const int orig = (blockIdx.z * ny + blockIdx.y) * nx + blockIdx.x;
  const int logical = (orig & 7) * (nwg >> 3) + (orig >> 3);
  const int lx = logical % nx;
  const int rest = logical / nx;
  const int ly = rest % ny, lz = rest / ny;
  const bf16* W = (lz == 0) ? Wq : (lz == 1) ? Wk : Wv;
  bf16* out = (lz == 0) ? q : (lz == 1) ? k : v;
  gemm_body<true>(A, W, out, CBT, CD, CD, ly * 128, lx * 128);
}

__global__ __launch_bounds__(256) void k_gemm_out(
    const bf16* __restrict__ A, const bf16* __restrict__ W, float* __restrict__ out) {
  const int nx = gridDim.x, ny = gridDim.y;
  const int nwg = nx * ny;
  const int orig = blockIdx.y * nx + blockIdx.x;
  const int logical = (orig & 7) * (nwg >> 3) + (orig >> 3);
  const int lx = logical % nx, ly = logical / nx;
  gemm_body<false>(A, W, out, CBT, CD, CD, ly * 128, lx * 128);
}

// ---------------- rotary, in place; q scaled by HD^-0.5 * log2(e) ----------------
// (S = q·k then lands directly in log2 units -> exp2 without per-element mul)
__global__ __launch_bounds__(256) void k_rotary(bf16* __restrict__ q, bf16* __restrict__ k,
                                                const float* __restrict__ cosb,
                                                const float* __restrict__ sinb) {
  const int bt = blockIdx.x;
  const int t = bt & (CT - 1);
  const size_t rowoff = (size_t)bt * CD;
  const float* cr = cosb + (size_t)t * CHD;
  const float* sr = sinb + (size_t)t * CHD;
  for (int i = threadIdx.x; i < 288; i += 256) {
    int tensor = i / 144;
    int rem = i - tensor * 144;
    int h = rem / 18, jg = rem % 18;
    int j = jg * 4;
    float scl = tensor ? 1.0f : 0.120224587f;  // SCALE * log2(e) folded into q
    bf16* base = (tensor ? k : q) + rowoff + h * CHD;
    bf16x4 a = *(bf16x4*)&base[j];
    bf16x4 b2 = *(bf16x4*)&base[j + 72];
    f32x4 c1 = *(const f32x4*)&cr[j];
    f32x4 s1 = *(const f32x4*)&sr[j];
    f32x4 c2 = *(const f32x4*)&cr[j + 72];
    f32x4 s2 = *(const f32x4*)&sr[j + 72];
    bf16x4 o1, o2;
    for (int r = 0; r < 4; ++r) {
      float av = (float)a[r], bv = (float)b2[r];
      o1[r] = (bf16)((av * c1[r] - bv * s1[r]) * scl);
      o2[r] = (bf16)((bv * c2[r] + av * s2[r]) * scl);
    }
    *(bf16x4*)&base[j] = o1;
    *(bf16x4*)&base[j + 72] = o2;
  }
}

// ---------------- V transpose: v_lin[b][t][h*144+hd] -> vT[bh][hd][t] ----------------
__global__ __launch_bounds__(256) void k_vtrans(const bf16* __restrict__ v, bf16* __restrict__ vT) {
  __shared__ bf16 tile[64][152];
  const int bh = blockIdx.y;
  const int b = bh >> 3, h = bh & 7;
  const int t0 = blockIdx.x * 64;
  for (int i8 = threadIdx.x; i8 < 64 * 18; i8 += 256) {
    int r = i8 / 18, c8 = i8 % 18;
    *(bf16x8*)&tile[r][c8 * 8] =
        *(const bf16x8*)&v[((size_t)(b * CT + t0 + r)) * CD + h * CHD + c8 * 8];
  }
  __syncthreads();
  for (int o = threadIdx.x; o < CHD * 64; o += 256) {
    int hd = o / 64, j = o & 63;
    vT[((size_t)(bh * CHD + hd)) * CT + t0 + j] = tile[j][hd];
  }
}

// ---------------- P fragment builder: S^T C-regs -> PV B-frags, in-register ----------
// s is in log2 units (LOG2E folded into q at rotary).
DEVI void build_pfrag(const f32x16& s, float m, float& ps, bf16x8& f0, bf16x8& f1) {
  uint32_t pk[8];
#pragma unroll
  for (int a = 0; a < 8; ++a) {
    float p0 = exp2f(s[2 * a] - m);
    float p1 = exp2f(s[2 * a + 1] - m);
    ps += p0 + p1;
    pk[a] = cvtpk(p0, p1);
  }
  u32x2 r02 = __builtin_amdgcn_permlane32_swap(pk[0], pk[2], false, false);
  u32x2 r13 = __builtin_amdgcn_permlane32_swap(pk[1], pk[3], false, false);
  u32x2 r46 = __builtin_amdgcn_permlane32_swap(pk[4], pk[6], false, false);
  u32x2 r57 = __builtin_amdgcn_permlane32_swap(pk[5], pk[7], false, false);
  u32x4 w0 = {r02[0], r13[0], r02[1], r13[1]};
  u32x4 w1 = {r46[0], r57[0], r46[1], r57[1]};
  f0 = __builtin_bit_cast(bf16x8, w0);
  f1 = __builtin_bit_cast(bf16x8, w1);
}

// ILP-friendly 32-element max over two f32x16 (quads -> tree; fusable to v_max3)
DEVI float max32(const f32x16& s0, const f32x16& s1) {
  float q0 = fmaxf(fmaxf(s0[0], s0[1]), fmaxf(s0[2], s0[3]));
  float q1 = fmaxf(fmaxf(s0[4], s0[5]), fmaxf(s0[6], s0[7]));
  float q2 = fmaxf(fmaxf(s0[8], s0[9]), fmaxf(s0[10], s0[11]));
  float q3 = fmaxf(fmaxf(s0[12], s0[13]), fmaxf(s0[14], s0[15]));
  float q4 = fmaxf(fmaxf(s1[0], s1[1]), fmaxf(s1[2], s1[3]));
  float q5 = fmaxf(fmaxf(s1[4], s1[5]), fmaxf(s1[6], s1[7]));
  float q6 = fmaxf(fmaxf(s1[8], s1[9]), fmaxf(s1[10], s1[11]));
  float q7 = fmaxf(fmaxf(s1[12], s1[13]), fmaxf(s1[14], s1[15]));
  return fmaxf(fmaxf(fmaxf(q0, q1), fmaxf(q2, q3)),
               fmaxf(fmaxf(q4, q5), fmaxf(q6, q7)));
}

// ---------------- flash attention: 2-phase double-buffered gload_lds pipeline ------
// (round-6 structure — T15 reverted; log2-softmax + tree-max kept)
// grid: 256 blocks (bh-XCD affinity), 512 threads = 8 waves x 32 q-rows (256 q/block).
// Ks[2][64][384B] (XOR-swizzled via pre-swizzled source). Vs[2][160][128B].
// Per tile: issue gload_lds for t+1 into buf^1; compute from buf; single barrier.
__global__ __launch_bounds__(512, 2) void k_attn(const bf16* __restrict__ qg,
                                                 const bf16* __restrict__ kg,
                                                 const bf16* __restrict__ vT,
                                                 bf16* __restrict__ og) {
  const int lin = blockIdx.x;
  const int xcd = lin & 7, idx = lin >> 3;
  const int bh = ((idx & 3) << 3) | xcd;   // 4 heads per XCD -> K/V L2-resident
  const int qx = idx >> 2;
  const int b = bh >> 3, h = bh & 7;
  const int q0 = qx << 8;
  const int tid = threadIdx.x, lane = tid & 63, wq = tid >> 6;
  const int l31 = lane & 31, hi = lane >> 5;
  const int hi16 = hi * 16;
  const int kxor = (l31 & 7) << 4;

  constexpr int KBUF = 64 * 192;    // 12288 els = 24576 B
  constexpr int VBUF = 160 * 64;    // 10240 els = 20480 B
  __shared__ __align__(16) bf16 Ks[2 * KBUF];   // 49152 B
  __shared__ __align__(16) bf16 Vs[2 * VBUF];   // 40960 B  (total 90112 B)

  // Q fragments (B-frag: col=q=l31, k = ks*16 + hi*8 + e), 9 k-steps (144 = 9*16)
  bf16x8 qf[9];
  {
    const bf16* qbase = qg + (size_t)(b * CT + q0 + wq * 32 + l31) * CD + h * CHD + hi * 8;
#pragma unroll
    for (int ks = 0; ks < 9; ++ks) qf[ks] = *(const bf16x8*)&qbase[ks * 16];
  }

  // staging precompute: LDS dest linear, global source pre-swizzled (m173 pattern).
  const bf16* ksrc[3];
  const bf16* vsrc[3];
  int kldo[3], vldo[3];
#pragma unroll
  for (int it = 0; it < 3; ++it) {
    int c = tid + it * 512;
    int krow = c / 24, kj = c - krow * 24;
    int kcol = (kj * 16) ^ ((krow & 7) << 4);
    if (kcol >= 288) kcol = 0;  // pad slot: valid addr, never read
    ksrc[it] = kg + (size_t)(b * CT + krow) * CD + h * CHD + (kcol >> 1);
    kldo[it] = ((tid & ~63) + it * 512) * 8;
    int vr = c >> 3, vj = c & 7;
    int vcol = (vj * 16) ^ ((vr & 7) << 4);
    if (vr > 143) vr = 143;  // it2 tail unused (guarded), keep ptr valid
    vsrc[it] = vT + (size_t)(bh * CHD + vr) * CT + (vcol >> 1);
    vldo[it] = ((tid & ~63) + it * 512) * 8;
  }
  const bool vok2 = (tid < 128);  // wave-uniform guard for V chunk set #2

  // zero V pad rows (144..159) in BOTH buffers — staged loads never touch them
  if (tid < 256) {
    u32x4 z = {0u, 0u, 0u, 0u};
    int bsel = tid >> 7, off = tid & 127;
    *(u32x4*)(Vs + bsel * VBUF + 144 * 64 + off * 8) = z;
  }

#define STAGE_TILE(kv, buf)                                                 \
  do {                                                                      \
    bf16* Kn = Ks + (buf)*KBUF;                                             \
    bf16* Vn = Vs + (buf)*VBUF;                                             \
    _Pragma("unroll") for (int it = 0; it < 3; ++it)                        \
        gload_lds16(ksrc[it] + (size_t)(kv)*CD, Kn + kldo[it]);             \
    _Pragma("unroll") for (int it = 0; it < 2; ++it)                        \
        gload_lds16(vsrc[it] + (kv), Vn + vldo[it]);                        \
    if (vok2) gload_lds16(vsrc[2] + (kv), Vn + vldo[2]);                    \
  } while (0)

  // prologue: stage tile 0 into buf 0
  STAGE_TILE(0, 0);
  __syncthreads();  // tile 0 staged, pad zeros visible

  f32x16 oacc[5];
#pragma unroll
  for (int u = 0; u < 5; ++u) oacc[u] = zero16();
  float mrow = -__builtin_inff();
  float lsum = 0.f;

  int cur = 0;
  for (int t = 0; t < 32; ++t) {
    bf16* Kc = Ks + cur * KBUF;
    bf16* Vc = Vs + cur * VBUF;

    // T3 issue-early: stage tile t+1 into the other buffer (no wait here)
    if (t < 31) STAGE_TILE((t + 1) << 6, cur ^ 1);
    __builtin_amdgcn_sched_barrier(0);  // pin stage issue before compute

    // S^T = K * Q^T : two 32-key tiles (result in log2 units)
    const char* kr0 = (const char*)Kc + (size_t)l31 * 384;
    const char* kr1 = kr0 + 32 * 384;
    f32x16 s0 = zero16(), s1 = zero16();
    __builtin_amdgcn_s_setprio(1);
#pragma unroll
    for (int ks = 0; ks < 9; ++ks) {
      int off = (ks * 32 + hi16) ^ kxor;
      s0 = mfma32(*(const bf16x8*)(kr0 + off), qf[ks], s0);
      s1 = mfma32(*(const bf16x8*)(kr1 + off), qf[ks], s1);
    }
    __builtin_amdgcn_s_setprio(0);

    // online softmax (lane-local; partner lane^32 holds other 32 keys of same q)
    float mt = max32(s0, s1);
    mt = fmaxf(mt, __shfl_xor(mt, 32));

    if (mt > mrow + 8.0f) {  // defer-max (log2 units; P bounded by 2^8)
      float alpha = exp2f(mrow - mt);
      lsum *= alpha;
#pragma unroll
      for (int u = 0; u < 5; ++u) oacc[u] = oacc[u] * alpha;
      mrow = mt;
    }

    float ps = 0.f;
    bf16x8 pf0, pf1, pf2, pf3;
    build_pfrag(s0, mrow, ps, pf0, pf1);
    build_pfrag(s1, mrow, ps, pf2, pf3);
    ps += __shfl_xor(ps, 32);
    lsum += ps;

    // O^T += V^T * P^T
    __builtin_amdgcn_s_setprio(1);
#pragma unroll
    for (int u = 0; u < 5; ++u) {
      const char* vrow = (const char*)Vc + (size_t)(u * 32 + l31) * 128;
      oacc[u] = mfma32(*(const bf16x8*)(vrow + ((0 * 32 + hi16) ^ kxor)), pf0, oacc[u]);
      oacc[u] = mfma32(*(const bf16x8*)(vrow + ((1 * 32 + hi16) ^ kxor)), pf1, oacc[u]);
      oacc[u] = mfma32(*(const bf16x8*)(vrow + ((2 * 32 + hi16) ^ kxor)), pf2, oacc[u]);
      oacc[u] = mfma32(*(const bf16x8*)(vrow + ((3 * 32 + hi16) ^ kxor)), pf3, oacc[u]);
    }
    __builtin_amdgcn_s_setprio(0);

    __syncthreads();  // reads of buf[cur] done + my prefetch drained
    cur ^= 1;
  }
#undef STAGE_TILE

  // normalize + store: lane owns q-col = l31; C rows hd = u*32+(reg&3)+8*(reg>>2)+4*hi
  float inv = 1.0f / lsum;
  bf16* ob = og + (size_t)(b * CT + q0 + wq * 32 + l31) * CD + h * CHD;
#pragma unroll
  for (int u = 0; u < 5; ++u) {
#pragma unroll
    for (int pr = 0; pr < 8; ++pr) {
      if (u == 4 && pr >= 4) continue;  // hd >= 144 is pad
      int hd = u * 32 + ((2 * pr) & 3) + 8 * (pr >> 1) + 4 * hi;
      bf16x2 w;
      w[0] = (bf16)(oacc[u][2 * pr] * inv);
      w[1] = (bf16)(oacc[u][2 * pr + 1] * inv);
      *(bf16x2*)&ob[hd] = w;
    }
  }
}

// ---------------- launcher ----------------
extern "C" void kernel_launch(void* const* d_in, const int* in_sizes, int n_in,
                              void* d_out, int out_size, void* d_ws, size_t ws_size,
                              hipStream_t stream) {
  const float* x = (const float*)d_in[0];
  const float* cosb = (const float*)d_in[1];
  const float* sinb = (const float*)d_in[2];
  const float* Wq = (const float*)d_in[3];
  const float* Wk = (const float*)d_in[4];
  const float* Wv = (const float*)d_in[5];
  const float* Wo = (const float*)d_in[6];

  char* ws = (char*)d_ws;
  bf16* xb   = (bf16*)(ws + 0);           // reused as attention output (o_bt)
  bf16* wqb  = (bf16*)(ws + 18874368);
  bf16* wkb  = (bf16*)(ws + 21528576);
  bf16* wvb  = (bf16*)(ws + 24182784);
  bf16* wob  = (bf16*)(ws + 26836992);
  bf16* qlin = (bf16*)(ws + 29491200);
  bf16* klin = (bf16*)(ws + 48365568);
  bf16* vlin = (bf16*)(ws + 67239936);
  bf16* vT   = (bf16*)(ws + 86114304);

  // casts
  k_cast<<<4608, 256, 0, stream>>>(x, xb, CBT * CD / 8);
  k_cast4<<<dim3(648, 4), 256, 0, stream>>>(Wq, Wk, Wv, Wo, wqb, wkb, wvb, wob,
                                            CD * CD / 8);

  // QKV projections (fused over z, XCD-swizzled, 2-phase dbuf)
  k_gemm_qkv<<<dim3(CD / 128, CBT / 128, 3), 256, 0, stream>>>(xb, wqb, wkb, wvb,
                                                               qlin, klin, vlin);
  // rotary in place on q,k (q scaled by SCALE*log2e)
  k_rotary<<<CB * CT, 256, 0, stream>>>(qlin, klin, cosb, sinb);
  // V transpose
  k_vtrans<<<dim3(CT / 64, CB * CH), 256, 0, stream>>>(vlin, vT);
  // attention -> o (into xb region, [b][t][h*144+hd])
  k_attn<<<256, 512, 0, stream>>>(qlin, klin, vT, xb);
  // output projection (f32 out, XCD-swizzled, 2-phase dbuf)
  k_gemm_out<<<dim3(CD / 128, CBT / 128), 256, 0, stream>>>(xb, wob, (float*)d_out);
}

// Round 9
// 253.214 us; speedup vs baseline: 1.1130x; 1.0413x over previous
//
#include <hip/hip_runtime.h>
#include <cstdint>
#include <cstddef>

typedef __bf16 bf16;
typedef bf16 bf16x8 __attribute__((ext_vector_type(8)));
typedef bf16 bf16x4 __attribute__((ext_vector_type(4)));
typedef bf16 bf16x2 __attribute__((ext_vector_type(2)));
typedef float f32x4 __attribute__((ext_vector_type(4)));
typedef float f32x16 __attribute__((ext_vector_type(16)));
typedef uint32_t u32x2 __attribute__((ext_vector_type(2)));
typedef uint32_t u32x4 __attribute__((ext_vector_type(4)));

#define DEVI __device__ __forceinline__

// ---------------- constants ----------------
// B=4, T=2048, D=1152, H=8, HD=144, BT=8192
#define CB 4
#define CT 2048
#define CD 1152
#define CH 8
#define CHD 144
#define CBT 8192

DEVI void gload_lds16(const void* g, void* l) {
  __builtin_amdgcn_global_load_lds(
      (const __attribute__((address_space(1))) void*)g,
      (__attribute__((address_space(3))) void*)l, 16, 0, 0);
}

DEVI f32x4 mfma16(bf16x8 a, bf16x8 b, f32x4 c) {
  return __builtin_amdgcn_mfma_f32_16x16x32_bf16(a, b, c, 0, 0, 0);
}
DEVI f32x16 mfma32(bf16x8 a, bf16x8 b, f32x16 c) {
  return __builtin_amdgcn_mfma_f32_32x32x16_bf16(a, b, c, 0, 0, 0);
}

DEVI uint32_t cvtpk(float lo, float hi) {
  uint32_t r;
  asm("v_cvt_pk_bf16_f32 %0, %1, %2" : "=v"(r) : "v"(lo), "v"(hi));
  return r;
}

DEVI f32x16 zero16() {
  f32x16 z;
#pragma unroll
  for (int i = 0; i < 16; ++i) z[i] = 0.f;
  return z;
}

// ---------------- cast f32 -> bf16 (8 els / thread) ----------------
__global__ __launch_bounds__(256) void k_cast(const float* __restrict__ in,
                                              bf16* __restrict__ out, int n8) {
  int i = blockIdx.x * 256 + threadIdx.x;
  if (i >= n8) return;
  const float4* p = (const float4*)in + (size_t)i * 2;
  float4 a = p[0], b = p[1];
  bf16x8 o;
  o[0] = (bf16)a.x; o[1] = (bf16)a.y; o[2] = (bf16)a.z; o[3] = (bf16)a.w;
  o[4] = (bf16)b.x; o[5] = (bf16)b.y; o[6] = (bf16)b.z; o[7] = (bf16)b.w;
  ((bf16x8*)out)[i] = o;
}

// 4 weight casts in one launch (blockIdx.y selects tensor)
__global__ __launch_bounds__(256) void k_cast4(
    const float* __restrict__ a, const float* __restrict__ b,
    const float* __restrict__ c, const float* __restrict__ d,
    bf16* __restrict__ oa, bf16* __restrict__ ob,
    bf16* __restrict__ oc, bf16* __restrict__ od, int n8) {
  int w = blockIdx.y;
  const float* in = (w == 0) ? a : (w == 1) ? b : (w == 2) ? c : d;
  bf16* out = (w == 0) ? oa : (w == 1) ? ob : (w == 2) ? oc : od;
  int i = blockIdx.x * 256 + threadIdx.x;
  if (i >= n8) return;
  const float4* p = (const float4*)in + (size_t)i * 2;
  float4 x = p[0], y = p[1];
  bf16x8 o;
  o[0] = (bf16)x.x; o[1] = (bf16)x.y; o[2] = (bf16)x.z; o[3] = (bf16)x.w;
  o[4] = (bf16)y.x; o[5] = (bf16)y.y; o[6] = (bf16)y.z; o[7] = (bf16)y.w;
  ((bf16x8*)out)[i] = o;
}

// ---------------- GEMM C[M,N] = A[M,K] * W[N,K]^T  (bf16 in, f32 acc) ----------------
// 128x128 tile, BK=32, 2-phase double-buffered staging.
template <bool BF16_OUT>
DEVI void gemm_body(const bf16* __restrict__ A, const bf16* __restrict__ W,
                    void* __restrict__ Cout, int M, int N, int K,
                    int bm0, int bn0) {
  constexpr int TBUF = 128 * 40;  // 5120 els = 10240 B per tensor per buffer
  __shared__ __align__(16) bf16 As[2 * TBUF];
  __shared__ __align__(16) bf16 Bs[2 * TBUF];
  const int tid = threadIdx.x;
  const int lane = tid & 63, wid = tid >> 6;
  const int l15 = lane & 15, g = lane >> 4;
  const int wm = wid >> 1, wn = wid & 1;

  // staging source precompute (li < 640 active chunks of 8 els)
  const bf16* asrc[3];
  const bf16* wsrc[3];
  int ldo[3];
  bool on[3];
#pragma unroll
  for (int c = 0; c < 3; ++c) {
    int li = tid + (c << 8);
    on[c] = (li < 640);
    int li2 = on[c] ? li : 0;
    int e0 = li2 << 3;
    int row = e0 / 40, col = e0 % 40;
    if (col >= 32) col = 24;  // pad slot: valid addr, never read as fragment
    asrc[c] = &A[(size_t)(bm0 + row) * K + col];
    wsrc[c] = &W[(size_t)(bn0 + row) * K + col];
    ldo[c] = (li2 & ~63) * 8;
  }

#define G_STAGE(k0, buf)                                                     \
  do {                                                                       \
    bf16* Ad = As + (buf)*TBUF;                                              \
    bf16* Bd = Bs + (buf)*TBUF;                                              \
    _Pragma("unroll") for (int c = 0; c < 3; ++c) if (on[c]) {               \
      gload_lds16(asrc[c] + (k0), Ad + ldo[c]);                              \
      gload_lds16(wsrc[c] + (k0), Bd + ldo[c]);                              \
    }                                                                        \
  } while (0)

  f32x4 acc[4][4];
  for (int mi = 0; mi < 4; ++mi)
    for (int ni = 0; ni < 4; ++ni) {
      acc[mi][ni][0] = 0.f; acc[mi][ni][1] = 0.f;
      acc[mi][ni][2] = 0.f; acc[mi][ni][3] = 0.f;
    }

  const int nk = K >> 5;  // 36
  G_STAGE(0, 0);
  __syncthreads();

  int cur = 0;
  for (int kt = 0; kt < nk; ++kt) {
    if (kt + 1 < nk) G_STAGE((kt + 1) << 5, cur ^ 1);
    __builtin_amdgcn_sched_barrier(0);  // pin prefetch issue before compute

    const bf16* Ac = As + cur * TBUF;
    const bf16* Bc = Bs + cur * TBUF;
    bf16x8 af[4], bfr[4];
    for (int mi = 0; mi < 4; ++mi)
      af[mi] = *(const bf16x8*)&Ac[(wm * 64 + mi * 16 + l15) * 40 + g * 8];
    for (int ni = 0; ni < 4; ++ni)
      bfr[ni] = *(const bf16x8*)&Bc[(wn * 64 + ni * 16 + l15) * 40 + g * 8];
    __builtin_amdgcn_s_setprio(1);
    for (int mi = 0; mi < 4; ++mi)
      for (int ni = 0; ni < 4; ++ni)
        acc[mi][ni] = mfma16(af[mi], bfr[ni], acc[mi][ni]);
    __builtin_amdgcn_s_setprio(0);
    __syncthreads();  // drains my prefetch (vm) + everyone's reads (lgkm)
    cur ^= 1;
  }
#undef G_STAGE

  for (int mi = 0; mi < 4; ++mi)
    for (int ni = 0; ni < 4; ++ni)
      for (int r = 0; r < 4; ++r) {
        int rowg = bm0 + wm * 64 + mi * 16 + g * 4 + r;
        int colg = bn0 + wn * 64 + ni * 16 + l15;
        float v = acc[mi][ni][r];
        if (BF16_OUT)
          ((bf16*)Cout)[(size_t)rowg * N + colg] = (bf16)v;
        else
          ((float*)Cout)[(size_t)rowg * N + colg] = v;
      }
}

__global__ __launch_bounds__(256) void k_gemm_qkv(
    const bf16* __restrict__ A, const bf16* __restrict__ Wq,
    const bf16* __restrict__ Wk, const bf16* __restrict__ Wv,
    bf16* __restrict__ q, bf16* __restrict__ k, bf16* __restrict__ v) {
  // T1 bijective XCD swizzle (nwg = 1728, %8 == 0)
  const int nx = gridDim.x, ny = gridDim.y;
  const int nwg = nx * ny * gridDim.z;
  const int orig = (blockIdx.z * ny + blockIdx.y) * nx + blockIdx.x;
  const int logical = (orig & 7) * (nwg >> 3) + (orig >> 3);
  const int lx = logical % nx;
  const int rest = logical / nx;
  const int ly = rest % ny, lz = rest / ny;
  const bf16* W = (lz == 0) ? Wq : (lz == 1) ? Wk : Wv;
  bf16* out = (lz == 0) ? q : (lz == 1) ? k : v;
  gemm_body<true>(A, W, out, CBT, CD, CD, ly * 128, lx * 128);
}

__global__ __launch_bounds__(256) void k_gemm_out(
    const bf16* __restrict__ A, const bf16* __restrict__ W, float* __restrict__ out) {
  const int nx = gridDim.x, ny = gridDim.y;
  const int nwg = nx * ny;
  const int orig = blockIdx.y * nx + blockIdx.x;
  const int logical = (orig & 7) * (nwg >> 3) + (orig >> 3);
  const int lx = logical % nx, ly = logical / nx;
  gemm_body<false>(A, W, out, CBT, CD, CD, ly * 128, lx * 128);
}

// ---------------- rotary, in place; q scaled by HD^-0.5 * log2(e) ----------------
__global__ __launch_bounds__(256) void k_rotary(bf16* __restrict__ q, bf16* __restrict__ k,
                                                const float* __restrict__ cosb,
                                                const float* __restrict__ sinb) {
  const int bt = blockIdx.x;
  const int t = bt & (CT - 1);
  const size_t rowoff = (size_t)bt * CD;
  const float* cr = cosb + (size_t)t * CHD;
  const float* sr = sinb + (size_t)t * CHD;
  for (int i = threadIdx.x; i < 288; i += 256) {
    int tensor = i / 144;
    int rem = i - tensor * 144;
    int h = rem / 18, jg = rem % 18;
    int j = jg * 4;
    float scl = tensor ? 1.0f : 0.120224587f;  // SCALE * log2(e) folded into q
    bf16* base = (tensor ? k : q) + rowoff + h * CHD;
    bf16x4 a = *(bf16x4*)&base[j];
    bf16x4 b2 = *(bf16x4*)&base[j + 72];
    f32x4 c1 = *(const f32x4*)&cr[j];
    f32x4 s1 = *(const f32x4*)&sr[j];
    f32x4 c2 = *(const f32x4*)&cr[j + 72];
    f32x4 s2 = *(const f32x4*)&sr[j + 72];
    bf16x4 o1, o2;
    for (int r = 0; r < 4; ++r) {
      float av = (float)a[r], bv = (float)b2[r];
      o1[r] = (bf16)((av * c1[r] - bv * s1[r]) * scl);
      o2[r] = (bf16)((bv * c2[r] + av * s2[r]) * scl);
    }
    *(bf16x4*)&base[j] = o1;
    *(bf16x4*)&base[j + 72] = o2;
  }
}

// ---------------- V transpose: v_lin[b][t][h*144+hd] -> vT[bh][hd][t] ----------------
__global__ __launch_bounds__(256) void k_vtrans(const bf16* __restrict__ v, bf16* __restrict__ vT) {
  __shared__ bf16 tile[64][152];
  const int bh = blockIdx.y;
  const int b = bh >> 3, h = bh & 7;
  const int t0 = blockIdx.x * 64;
  for (int i8 = threadIdx.x; i8 < 64 * 18; i8 += 256) {
    int r = i8 / 18, c8 = i8 % 18;
    *(bf16x8*)&tile[r][c8 * 8] =
        *(const bf16x8*)&v[((size_t)(b * CT + t0 + r)) * CD + h * CHD + c8 * 8];
  }
  __syncthreads();
  for (int o = threadIdx.x; o < CHD * 64; o += 256) {
    int hd = o / 64, j = o & 63;
    vT[((size_t)(bh * CHD + hd)) * CT + t0 + j] = tile[j][hd];
  }
}

// ---------------- P fragment builder: S^T C-regs -> PV B-frags, in-register ----------
// s is in log2 units (LOG2E folded into q at rotary).
DEVI void build_pfrag(const f32x16& s, float m, float& ps, bf16x8& f0, bf16x8& f1) {
  uint32_t pk[8];
#pragma unroll
  for (int a = 0; a < 8; ++a) {
    float p0 = exp2f(s[2 * a] - m);
    float p1 = exp2f(s[2 * a + 1] - m);
    ps += p0 + p1;
    pk[a] = cvtpk(p0, p1);
  }
  u32x2 r02 = __builtin_amdgcn_permlane32_swap(pk[0], pk[2], false, false);
  u32x2 r13 = __builtin_amdgcn_permlane32_swap(pk[1], pk[3], false, false);
  u32x2 r46 = __builtin_amdgcn_permlane32_swap(pk[4], pk[6], false, false);
  u32x2 r57 = __builtin_amdgcn_permlane32_swap(pk[5], pk[7], false, false);
  u32x4 w0 = {r02[0], r13[0], r02[1], r13[1]};
  u32x4 w1 = {r46[0], r57[0], r46[1], r57[1]};
  f0 = __builtin_bit_cast(bf16x8, w0);
  f1 = __builtin_bit_cast(bf16x8, w1);
}

// ILP-friendly 32-element max over two f32x16 (quads -> tree; fusable to v_max3)
DEVI float max32(const f32x16& s0, const f32x16& s1) {
  float q0 = fmaxf(fmaxf(s0[0], s0[1]), fmaxf(s0[2], s0[3]));
  float q1 = fmaxf(fmaxf(s0[4], s0[5]), fmaxf(s0[6], s0[7]));
  float q2 = fmaxf(fmaxf(s0[8], s0[9]), fmaxf(s0[10], s0[11]));
  float q3 = fmaxf(fmaxf(s0[12], s0[13]), fmaxf(s0[14], s0[15]));
  float q4 = fmaxf(fmaxf(s1[0], s1[1]), fmaxf(s1[2], s1[3]));
  float q5 = fmaxf(fmaxf(s1[4], s1[5]), fmaxf(s1[6], s1[7]));
  float q6 = fmaxf(fmaxf(s1[8], s1[9]), fmaxf(s1[10], s1[11]));
  float q7 = fmaxf(fmaxf(s1[12], s1[13]), fmaxf(s1[14], s1[15]));
  return fmaxf(fmaxf(fmaxf(q0, q1), fmaxf(q2, q3)),
               fmaxf(fmaxf(q4, q5), fmaxf(q6, q7)));
}

// ---------------- flash attention: 2-phase dbuf, 2 blocks/CU ----------------------
// grid: 512 blocks (bh-XCD affinity), 256 threads = 4 waves x 32 q-rows (128 q/block).
// Ks[2][64][288B] — NO pad; XOR swizzle confined to granules 0..15 (granule 16,17
// unswizzled). Vs[2][160][128B]. LDS total 77824 B -> 2 blocks/CU: two independent
// barrier domains per CU at staggered phases overlap MFMA/VALU/staging.
__global__ __launch_bounds__(256, 2) void k_attn(const bf16* __restrict__ qg,
                                                 const bf16* __restrict__ kg,
                                                 const bf16* __restrict__ vT,
                                                 bf16* __restrict__ og) {
  const int lin = blockIdx.x;
  const int xcd = lin & 7, idx = lin >> 3;   // idx in [0,64)
  const int bh = ((idx & 3) << 3) | xcd;     // 4 heads per XCD -> K/V L2-resident
  const int qx = idx >> 2;                   // [0,16) q-blocks of 128
  const int b = bh >> 3, h = bh & 7;
  const int q0 = qx << 7;
  const int tid = threadIdx.x, lane = tid & 63, wq = tid >> 6;  // 4 waves
  const int l31 = lane & 31, hi = lane >> 5;
  const int hi16 = hi * 16;
  const int kx7 = l31 & 7;
  const int kxor = kx7 << 4;

  constexpr int KBUF = 64 * 144;    // 9216 els = 18432 B (288 B/row)
  constexpr int VBUF = 160 * 64;    // 10240 els = 20480 B
  __shared__ __align__(16) bf16 Ks[2 * KBUF];   // 36864 B
  __shared__ __align__(16) bf16 Vs[2 * VBUF];   // 40960 B  (total 77824 B)

  // Q fragments (B-frag: col=q=l31, k = ks*16 + hi*8 + e), 9 k-steps (144 = 9*16)
  bf16x8 qf[9];
  {
    const bf16* qbase = qg + (size_t)(b * CT + q0 + wq * 32 + l31) * CD + h * CHD + hi * 8;
#pragma unroll
    for (int ks = 0; ks < 9; ++ks) qf[ks] = *(const bf16x8*)&qbase[ks * 16];
  }

  // staging precompute: LDS dest linear, global source pre-swizzled.
  // K: 64 rows x 18 granules = 1152 chunks; V: 144 rows x 8 = 1152.
  // 256 threads x 4 sets + half-set (tid<128).
  const bf16* ksrc[5];
  const bf16* vsrc[5];
  int kldo[5], vldo[5];
#pragma unroll
  for (int it = 0; it < 5; ++it) {
    int c = tid + it * 256;
    if (c >= 1152) c = 0;  // dead lanes (guarded at use)
    int krow = c / 18, kj = c - krow * 18;
    int kgr = (kj < 16) ? (kj ^ (krow & 7)) : kj;  // involution within 16-granule grp
    ksrc[it] = kg + (size_t)(b * CT + krow) * CD + h * CHD + kgr * 8;
    kldo[it] = (c & ~63) * 8;
    int vr = c >> 3, vj = c & 7;
    int vgr = vj ^ (vr & 7);
    vsrc[it] = vT + (size_t)(bh * CHD + vr) * CT + vgr * 8;
    vldo[it] = (c & ~63) * 8;
  }

  // zero V pad rows (144..159) in BOTH buffers — staged loads never touch them
  {
    u32x4 z = {0u, 0u, 0u, 0u};
    int bsel = tid >> 7, off = tid & 127;
    *(u32x4*)(Vs + bsel * VBUF + 144 * 64 + off * 8) = z;
  }

#define STAGE_TILE(kv, buf)                                                 \
  do {                                                                      \
    bf16* Kn = Ks + (buf)*KBUF;                                             \
    bf16* Vn = Vs + (buf)*VBUF;                                             \
    _Pragma("unroll") for (int it = 0; it < 4; ++it) {                      \
      gload_lds16(ksrc[it] + (size_t)(kv)*CD, Kn + kldo[it]);               \
      gload_lds16(vsrc[it] + (kv), Vn + vldo[it]);                          \
    }                                                                       \
    if (tid < 128) {                                                        \
      gload_lds16(ksrc[4] + (size_t)(kv)*CD, Kn + kldo[4]);                 \
      gload_lds16(vsrc[4] + (kv), Vn + vldo[4]);                            \
    }                                                                       \
  } while (0)

  // prologue: stage tile 0 into buf 0
  STAGE_TILE(0, 0);
  __syncthreads();  // tile 0 staged, pad zeros visible

  f32x16 oacc[5];
#pragma unroll
  for (int u = 0; u < 5; ++u) oacc[u] = zero16();
  float mrow = -__builtin_inff();
  float lsum = 0.f;

  int cur = 0;
  for (int t = 0; t < 32; ++t) {
    bf16* Kc = Ks + cur * KBUF;
    bf16* Vc = Vs + cur * VBUF;

    // issue-early: stage tile t+1 into the other buffer (no wait here)
    if (t < 31) STAGE_TILE((t + 1) << 6, cur ^ 1);
    __builtin_amdgcn_sched_barrier(0);  // pin stage issue before compute

    // S^T = K * Q^T : two 32-key tiles (result in log2 units)
    const char* kr0 = (const char*)Kc + (size_t)l31 * 288;
    const char* kr1 = kr0 + 32 * 288;
    f32x16 s0 = zero16(), s1 = zero16();
    __builtin_amdgcn_s_setprio(1);
#pragma unroll
    for (int ks = 0; ks < 9; ++ks) {
      int cc = 2 * ks + hi;
      int off = ((ks < 8) ? (cc ^ kx7) : cc) << 4;
      s0 = mfma32(*(const bf16x8*)(kr0 + off), qf[ks], s0);
      s1 = mfma32(*(const bf16x8*)(kr1 + off), qf[ks], s1);
    }
    __builtin_amdgcn_s_setprio(0);

    // online softmax (lane-local; partner lane^32 holds other 32 keys of same q)
    float mt = max32(s0, s1);
    mt = fmaxf(mt, __shfl_xor(mt, 32));

    if (mt > mrow + 8.0f) {  // defer-max (log2 units; P bounded by 2^8)
      float alpha = exp2f(mrow - mt);
      lsum *= alpha;
#pragma unroll
      for (int u = 0; u < 5; ++u) oacc[u] = oacc[u] * alpha;
      mrow = mt;
    }

    float ps = 0.f;
    bf16x8 pf0, pf1, pf2, pf3;
    build_pfrag(s0, mrow, ps, pf0, pf1);
    build_pfrag(s1, mrow, ps, pf2, pf3);
    ps += __shfl_xor(ps, 32);
    lsum += ps;

    // O^T += V^T * P^T
    __builtin_amdgcn_s_setprio(1);
#pragma unroll
    for (int u = 0; u < 5; ++u) {
      const char* vrow = (const char*)Vc + (size_t)(u * 32 + l31) * 128;
      oacc[u] = mfma32(*(const bf16x8*)(vrow + ((0 * 32 + hi16) ^ kxor)), pf0, oacc[u]);
      oacc[u] = mfma32(*(const bf16x8*)(vrow + ((1 * 32 + hi16) ^ kxor)), pf1, oacc[u]);
      oacc[u] = mfma32(*(const bf16x8*)(vrow + ((2 * 32 + hi16) ^ kxor)), pf2, oacc[u]);
      oacc[u] = mfma32(*(const bf16x8*)(vrow + ((3 * 32 + hi16) ^ kxor)), pf3, oacc[u]);
    }
    __builtin_amdgcn_s_setprio(0);

    __syncthreads();  // reads of buf[cur] done + my prefetch drained
    cur ^= 1;
  }
#undef STAGE_TILE

  // normalize + store: lane owns q-col = l31; C rows hd = u*32+(reg&3)+8*(reg>>2)+4*hi
  float inv = 1.0f / lsum;
  bf16* ob = og + (size_t)(b * CT + q0 + wq * 32 + l31) * CD + h * CHD;
#pragma unroll
  for (int u = 0; u < 5; ++u) {
#pragma unroll
    for (int pr = 0; pr < 8; ++pr) {
      if (u == 4 && pr >= 4) continue;  // hd >= 144 is pad
      int hd = u * 32 + ((2 * pr) & 3) + 8 * (pr >> 1) + 4 * hi;
      bf16x2 w;
      w[0] = (bf16)(oacc[u][2 * pr] * inv);
      w[1] = (bf16)(oacc[u][2 * pr + 1] * inv);
      *(bf16x2*)&ob[hd] = w;
    }
  }
}

// ---------------- launcher ----------------
extern "C" void kernel_launch(void* const* d_in, const int* in_sizes, int n_in,
                              void* d_out, int out_size, void* d_ws, size_t ws_size,
                              hipStream_t stream) {
  const float* x = (const float*)d_in[0];
  const float* cosb = (const float*)d_in[1];
  const float* sinb = (const float*)d_in[2];
  const float* Wq = (const float*)d_in[3];
  const float* Wk = (const float*)d_in[4];
  const float* Wv = (const float*)d_in[5];
  const float* Wo = (const float*)d_in[6];

  char* ws = (char*)d_ws;
  bf16* xb   = (bf16*)(ws + 0);           // reused as attention output (o_bt)
  bf16* wqb  = (bf16*)(ws + 18874368);
  bf16* wkb  = (bf16*)(ws + 21528576);
  bf16* wvb  = (bf16*)(ws + 24182784);
  bf16* wob  = (bf16*)(ws + 26836992);
  bf16* qlin = (bf16*)(ws + 29491200);
  bf16* klin = (bf16*)(ws + 48365568);
  bf16* vlin = (bf16*)(ws + 67239936);
  bf16* vT   = (bf16*)(ws + 86114304);

  // casts
  k_cast<<<4608, 256, 0, stream>>>(x, xb, CBT * CD / 8);
  k_cast4<<<dim3(648, 4), 256, 0, stream>>>(Wq, Wk, Wv, Wo, wqb, wkb, wvb, wob,
                                            CD * CD / 8);

  // QKV projections (fused over z, XCD-swizzled, 2-phase dbuf)
  k_gemm_qkv<<<dim3(CD / 128, CBT / 128, 3), 256, 0, stream>>>(xb, wqb, wkb, wvb,
                                                               qlin, klin, vlin);
  // rotary in place on q,k (q scaled by SCALE*log2e)
  k_rotary<<<CB * CT, 256, 0, stream>>>(qlin, klin, cosb, sinb);
  // V transpose
  k_vtrans<<<dim3(CT / 64, CB * CH), 256, 0, stream>>>(vlin, vT);
  // attention -> o (into xb region, [b][t][h*144+hd])
  k_attn<<<512, 256, 0, stream>>>(qlin, klin, vT, xb);
  // output projection (f32 out, XCD-swizzled, 2-phase dbuf)
  k_gemm_out<<<dim3(CD / 128, CBT / 128), 256, 0, stream>>>(xb, wob, (float*)d_out);
}